// Round 13
// baseline (402.634 us; speedup 1.0000x reference)
//
#include <hip/hip_runtime.h>
#include <hip/hip_bf16.h>

// Model_81956565942963: TCN + low-rank dynamic graph + linear head.
// B=16, L=512, N=64, D=128, S=32 x 16, r=8, P=96. f32 in/out.
// R13: tcn wave repartition (co-half x li-group, nt=4) -> each LDS hf
// fragment read feeds 4 MFMAs instead of 2; block ds_read_b128 count for
// activations drops 432->216 (the dominant LDS cost). z-means packed b32.
// Tail (g_gemm split-K, fused softmax out_partial, reduce) unchanged.

#define BATCH 16
#define SEQ 512
#define NVAR 64
#define DM 128
#define SEG 32
#define SCL 16
#define RNK 8
#define PRED 96
#define BN (BATCH * NVAR)   // 1024
#define ROWLEN (SEQ * DM)   // 65536

typedef unsigned short ushort_t;
typedef __attribute__((ext_vector_type(8))) short short8;   // 8 bf16
typedef __attribute__((ext_vector_type(4))) float f32x4;

__device__ inline float bf2f(ushort_t u) {
    union { unsigned int i; float f; } x;
    x.i = ((unsigned int)u) << 16;
    return x.f;
}
__device__ inline ushort_t f2bf(float f) {
    union { float f; unsigned int i; } u;
    u.f = f;
    unsigned int x = u.i;
    return (ushort_t)((x + 0x7fffu + ((x >> 16) & 1u)) >> 16);  // RNE
}
__device__ inline unsigned int pkbf(float a, float b) {  // packed bf16 pair
    __hip_bfloat162 h = __float22bfloat162_rn(make_float2(a, b));
    union { __hip_bfloat162 h2; unsigned int u; } c;
    c.h2 = h;
    return c.u;
}
__device__ inline float blo(unsigned int u) {
    union { unsigned int i; float f; } x;
    x.i = u << 16;
    return x.f;
}
__device__ inline float bhi(unsigned int u) {
    union { unsigned int i; float f; } x;
    x.i = u & 0xFFFF0000u;
    return x.f;
}
// gelu(x) = x * sigmoid(2t); rcp is v_rcp_f32 (1 inst) not the div sequence
__device__ inline float gelu_fast(float x) {
    float t = 0.7978845608028654f * x * (1.0f + 0.044715f * x * x);
    float e = __expf(-2.0f * t);
    return x * __builtin_amdgcn_rcpf(1.0f + e);
}

// ---------------- conv-weight prep: frag-major bf16 (+ regacc zero) ---------
__global__ __launch_bounds__(128) void wt_prep(
    const float* __restrict__ conv_w, ushort_t* __restrict__ WTf,
    float* __restrict__ regacc) {
    if (blockIdx.x == 0 && blockIdx.y == 0 && threadIdx.x == 0) regacc[0] = 0.f;
    int lt = blockIdx.x;    // 0..5 (layer*3+tap)
    int ci = blockIdx.y;    // 0..127
    int co = threadIdx.x;   // 0..127
    int kt = ci >> 5, quad = (ci >> 3) & 3, j = ci & 7;
    int ng = co >> 4, col = co & 15;
    int lane = quad * 16 + col;
    WTf[((((size_t)lt * 4 + kt) * 8 + ng) * 64 + lane) * 8 + j] =
        f2bf(conv_w[(size_t)lt * 16384 + (size_t)ci * 128 + co]);
}

// ---------------- fused TCN (MFMA) + segment means + e1/e2 ------------------
// Waves: ch = wv&1 (co half of 64), lg = wv>>1 (li group).
// Layer1 rows (li+16): lg0 -> 0..47 (3 tiles), lg1 -> 48..79 (2 tiles).
// Layer2 li: lg0 -> 0..31, lg1 -> 32..63 (2 tiles each).
__global__ __launch_bounds__(256, 4) void tcn_mfma(
    const float* __restrict__ x, const float* __restrict__ w_emb,
    const float* __restrict__ b_emb, const ushort_t* __restrict__ WTf,
    const float* __restrict__ conv_b,
    const float* __restrict__ gw1, const float* __restrict__ gb1,
    const float* __restrict__ gw2, const float* __restrict__ gb2,
    ushort_t* __restrict__ h2, float* __restrict__ e1, float* __restrict__ e2) {
    __shared__ __align__(16) ushort_t h0s[82 * 136];  // embed, row = li+18
    __shared__ __align__(16) ushort_t h1b[68 * 136];  // conv1 out, row = li+4
    float* zb = reinterpret_cast<float*>(h1b);        // alias: h1b dead by then

    int bn = blockIdx.x;
    int b = bn >> 6, n = bn & 63;
    int chunk = blockIdx.y;
    int l0 = chunk * 64;

    // ---- embed: 82 rows x 128 d (bf16), packed writes ----
    {
        const float* xb = x + (size_t)b * SEQ * NVAR + n;
#pragma unroll
        for (int i = 0; i < 21; ++i) {
            int q = threadIdx.x + 256 * i;
            if (q < 82 * 64) {
                int row = q >> 6, dp = (q & 63) * 2;
                int l = l0 + row - 18;
                unsigned int pk = 0;
                if (l >= 0) {
                    float xv = xb[(size_t)l * NVAR];
                    float2 wv2 = *reinterpret_cast<const float2*>(&w_emb[dp]);
                    float2 bv2 = *reinterpret_cast<const float2*>(&b_emb[dp]);
                    pk = pkbf(xv * wv2.x + bv2.x, xv * wv2.y + bv2.y);
                }
                *reinterpret_cast<unsigned int*>(&h0s[row * 136 + dp]) = pk;
            }
        }
    }
    __syncthreads();

    int lane = threadIdx.x & 63;
    int wv = threadIdx.x >> 6;
    int quad = lane >> 4;
    int col = lane & 15;
    int ch = wv & 1;        // co half
    int lg = wv >> 1;       // li group
    int cobase = ch * 64;

    // ---- layer 1: D[m=co][n=li]; one hf read feeds 4 MFMAs ----
    f32x4 acc1[3][4];
#pragma unroll
    for (int mt = 0; mt < 3; ++mt)
#pragma unroll
        for (int nt = 0; nt < 4; ++nt)
            acc1[mt][nt] = (f32x4){0.f, 0.f, 0.f, 0.f};
    int mtc1 = lg ? 2 : 3;
    int rb1 = lg * 48;

#pragma unroll
    for (int tap = 0; tap < 3; ++tap) {
#pragma unroll
        for (int kt = 0; kt < 4; ++kt) {
            short8 wf[4];
#pragma unroll
            for (int nt = 0; nt < 4; ++nt)
                wf[nt] = *(const short8*)(WTf +
                    ((((size_t)tap * 4 + kt) * 8 + ch * 4 + nt) * 64 + lane) * 8);
            int kc = kt * 32 + quad * 8;
#pragma unroll
            for (int mt = 0; mt < 3; ++mt) {
                if (mt < mtc1) {
                    short8 hf = *(const short8*)&h0s[
                        (rb1 + mt * 16 + col + tap) * 136 + kc];
#pragma unroll
                    for (int nt = 0; nt < 4; ++nt)
                        acc1[mt][nt] = __builtin_amdgcn_mfma_f32_16x16x32_bf16(
                            wf[nt], hf, acc1[mt][nt], 0, 0, 0);
                }
            }
        }
    }
    // epilogue 1: li = rb1 + mt*16 + col - 16; co = cobase + nt*16 + quad*4+r
    {
        float4 bias[4];
#pragma unroll
        for (int nt = 0; nt < 4; ++nt)
            bias[nt] = *reinterpret_cast<const float4*>(
                &conv_b[cobase + nt * 16 + quad * 4]);
#pragma unroll
        for (int mt = 0; mt < 3; ++mt) {
            if (mt < mtc1) {
                int li = rb1 + mt * 16 + col - 16;
                if (li >= -4) {
#pragma unroll
                    for (int nt = 0; nt < 4; ++nt) {
                        int co = cobase + nt * 16 + quad * 4;
                        uint2 pk;
                        if (l0 + li < 0) {
                            pk.x = 0u; pk.y = 0u;
                        } else {
                            uint2 res = *reinterpret_cast<const uint2*>(
                                &h0s[(li + 18) * 136 + co]);
                            float h0 = gelu_fast(acc1[mt][nt][0] + bias[nt].x) + blo(res.x);
                            float h1 = gelu_fast(acc1[mt][nt][1] + bias[nt].y) + bhi(res.x);
                            float h2v = gelu_fast(acc1[mt][nt][2] + bias[nt].z) + blo(res.y);
                            float h3 = gelu_fast(acc1[mt][nt][3] + bias[nt].w) + bhi(res.y);
                            pk.x = pkbf(h0, h1);
                            pk.y = pkbf(h2v, h3);
                        }
                        *reinterpret_cast<uint2*>(&h1b[(li + 4) * 136 + co]) = pk;
                    }
                }
            }
        }
    }
    __syncthreads();

    // ---- layer 2: li = lg*32 + mt*16 + col; tap t reads h1b row li+2t ----
    f32x4 acc2[2][4];
#pragma unroll
    for (int mt = 0; mt < 2; ++mt)
#pragma unroll
        for (int nt = 0; nt < 4; ++nt)
            acc2[mt][nt] = (f32x4){0.f, 0.f, 0.f, 0.f};
    int rb2 = lg * 32;

#pragma unroll
    for (int tap = 0; tap < 3; ++tap) {
#pragma unroll
        for (int kt = 0; kt < 4; ++kt) {
            short8 wf[4];
#pragma unroll
            for (int nt = 0; nt < 4; ++nt)
                wf[nt] = *(const short8*)(WTf +
                    ((((size_t)(3 + tap) * 4 + kt) * 8 + ch * 4 + nt) * 64 + lane) * 8);
            int kc = kt * 32 + quad * 8;
#pragma unroll
            for (int mt = 0; mt < 2; ++mt) {
                short8 hf = *(const short8*)&h1b[
                    (rb2 + mt * 16 + col + 2 * tap) * 136 + kc];
#pragma unroll
                for (int nt = 0; nt < 4; ++nt)
                    acc2[mt][nt] = __builtin_amdgcn_mfma_f32_16x16x32_bf16(
                        wf[nt], hf, acc2[mt][nt], 0, 0, 0);
            }
        }
    }
    // epilogue 2: h2 = gelu(y+bias)+h1 -> stage into h0s rows 0..63 (b64)
    {
        float4 bias[4];
#pragma unroll
        for (int nt = 0; nt < 4; ++nt)
            bias[nt] = *reinterpret_cast<const float4*>(
                &conv_b[DM + cobase + nt * 16 + quad * 4]);
#pragma unroll
        for (int mt = 0; mt < 2; ++mt) {
            int li = rb2 + mt * 16 + col;
#pragma unroll
            for (int nt = 0; nt < 4; ++nt) {
                int co = cobase + nt * 16 + quad * 4;
                uint2 res = *reinterpret_cast<const uint2*>(
                    &h1b[(li + 4) * 136 + co]);
                float h0 = gelu_fast(acc2[mt][nt][0] + bias[nt].x) + blo(res.x);
                float h1 = gelu_fast(acc2[mt][nt][1] + bias[nt].y) + bhi(res.x);
                float h2v = gelu_fast(acc2[mt][nt][2] + bias[nt].z) + blo(res.y);
                float h3 = gelu_fast(acc2[mt][nt][3] + bias[nt].w) + bhi(res.y);
                uint2 pk;
                pk.x = pkbf(h0, h1);
                pk.y = pkbf(h2v, h3);
                *reinterpret_cast<uint2*>(&h0s[li * 136 + co]) = pk;
            }
        }
    }
    __syncthreads();

    // ---- coalesced h2 store ----
    {
        ushort_t* orow = h2 + (size_t)bn * ROWLEN + (size_t)l0 * 128;
#pragma unroll
        for (int i = 0; i < 4; ++i) {
            int q = threadIdx.x + 256 * i;
            int row = q >> 4, c8 = (q & 15) * 8;
            *(short8*)&orow[row * 128 + c8] = *(const short8*)&h0s[row * 136 + c8];
        }
    }
    // ---- z: 4 segment means, packed b32 reads (zb aliases h1b) ----
    {
        int d2 = (threadIdx.x & 63) * 2;   // d pair
        int sg = threadIdx.x >> 6;         // segment 0..3
        float a0 = 0.0f, a1 = 0.0f;
#pragma unroll
        for (int c = 0; c < SCL; ++c) {
            unsigned int v = *reinterpret_cast<const unsigned int*>(
                &h0s[(sg * 16 + c) * 136 + d2]);
            a0 += blo(v);
            a1 += bhi(v);
        }
        zb[sg * 128 + d2] = a0 * (1.0f / 16.0f);
        zb[sg * 128 + d2 + 1] = a1 * (1.0f / 16.0f);
    }
    __syncthreads();
    // ---- e1/e2: 4 segs x 2 mats x 8 ranks ----
    if (threadIdx.x < 64) {
        int sl = threadIdx.x >> 4;
        int which = (threadIdx.x >> 3) & 1;
        int r = threadIdx.x & 7;
        const float* w = which ? gw2 : gw1;
        float a = 0.0f;
        for (int d = 0; d < DM; ++d) a += zb[sl * 128 + d] * w[d * RNK + r];
        a += (which ? gb2 : gb1)[r];
        int s = chunk * 4 + sl;
        (which ? e2 : e1)[(((size_t)b * SEG + s) * NVAR + n) * RNK + r] = a;
    }
}

// ---------------- G GEMM (MFMA): split-K x2, register-prefetch pipeline -----
__global__ __launch_bounds__(256) void g_gemm(
    const ushort_t* __restrict__ h2, const float* __restrict__ head_w,
    float* __restrict__ G) {
    __shared__ __align__(16) ushort_t As[64 * 72];  // [bn][k]
    __shared__ __align__(16) ushort_t Bs[96 * 72];  // [p][k]
    int s = blockIdx.x;
    int bnt = blockIdx.y;
    int kh = blockIdx.z;
    int bn0 = bnt * 64;
    int kbase = kh * 1024;
    int lane = threadIdx.x & 63, wv = threadIdx.x >> 6;
    int quad = lane >> 4, col = lane & 15;
    int mh = wv & 1;   // bn half (32)
    int ph = wv >> 1;  // p half (48)

    int arow = threadIdx.x >> 2, akq = (threadIdx.x & 3) * 16;
    const ushort_t* aptr =
        h2 + (size_t)(bn0 + arow) * ROWLEN + (size_t)s * 2048 + kbase + akq;
    const float* bbase = head_w + ((size_t)s * 2048 + kbase) * PRED;
    int bp0[3], bk2[3];
#pragma unroll
    for (int i = 0; i < 3; ++i) {
        int q = threadIdx.x + 256 * i;
        bp0[i] = (q % 24) * 4;
        bk2[i] = (q / 24) * 2;
    }

    f32x4 acc[3][2];  // [p-tile][bn-tile]
#pragma unroll
    for (int i = 0; i < 3; ++i)
#pragma unroll
        for (int j = 0; j < 2; ++j) acc[i][j] = (f32x4){0.f, 0.f, 0.f, 0.f};

    // ---- prefetch chunk 0 ----
    short8 pa0 = *(const short8*)aptr;
    short8 pa1 = *(const short8*)(aptr + 8);
    float4 pb0[3], pb1[3];
#pragma unroll
    for (int i = 0; i < 3; ++i) {
        const float* src = bbase + (size_t)bk2[i] * PRED + bp0[i];
        pb0[i] = *reinterpret_cast<const float4*>(src);
        pb1[i] = *reinterpret_cast<const float4*>(src + PRED);
    }
    *(short8*)&As[arow * 72 + akq] = pa0;
    *(short8*)&As[arow * 72 + akq + 8] = pa1;
#pragma unroll
    for (int i = 0; i < 3; ++i) {
        *reinterpret_cast<unsigned int*>(&Bs[(bp0[i] + 0) * 72 + bk2[i]]) = pkbf(pb0[i].x, pb1[i].x);
        *reinterpret_cast<unsigned int*>(&Bs[(bp0[i] + 1) * 72 + bk2[i]]) = pkbf(pb0[i].y, pb1[i].y);
        *reinterpret_cast<unsigned int*>(&Bs[(bp0[i] + 2) * 72 + bk2[i]]) = pkbf(pb0[i].z, pb1[i].z);
        *reinterpret_cast<unsigned int*>(&Bs[(bp0[i] + 3) * 72 + bk2[i]]) = pkbf(pb0[i].w, pb1[i].w);
    }
    __syncthreads();

    for (int kt = 0; kt < 16; ++kt) {
        if (kt < 15) {
            const ushort_t* ap = aptr + (kt + 1) * 64;
            pa0 = *(const short8*)ap;
            pa1 = *(const short8*)(ap + 8);
#pragma unroll
            for (int i = 0; i < 3; ++i) {
                const float* src =
                    bbase + (size_t)((kt + 1) * 64 + bk2[i]) * PRED + bp0[i];
                pb0[i] = *reinterpret_cast<const float4*>(src);
                pb1[i] = *reinterpret_cast<const float4*>(src + PRED);
            }
        }
#pragma unroll
        for (int kk = 0; kk < 2; ++kk) {
            int kc = kk * 32 + quad * 8;
            short8 pfr[3];
#pragma unroll
            for (int i = 0; i < 3; ++i)
                pfr[i] = *(const short8*)&Bs[(ph * 48 + i * 16 + col) * 72 + kc];
#pragma unroll
            for (int j = 0; j < 2; ++j) {
                short8 bnfr = *(const short8*)&As[(mh * 32 + j * 16 + col) * 72 + kc];
#pragma unroll
                for (int i = 0; i < 3; ++i)
                    acc[i][j] = __builtin_amdgcn_mfma_f32_16x16x32_bf16(pfr[i], bnfr, acc[i][j], 0, 0, 0);
            }
        }
        __syncthreads();
        if (kt < 15) {
            *(short8*)&As[arow * 72 + akq] = pa0;
            *(short8*)&As[arow * 72 + akq + 8] = pa1;
#pragma unroll
            for (int i = 0; i < 3; ++i) {
                *reinterpret_cast<unsigned int*>(&Bs[(bp0[i] + 0) * 72 + bk2[i]]) = pkbf(pb0[i].x, pb1[i].x);
                *reinterpret_cast<unsigned int*>(&Bs[(bp0[i] + 1) * 72 + bk2[i]]) = pkbf(pb0[i].y, pb1[i].y);
                *reinterpret_cast<unsigned int*>(&Bs[(bp0[i] + 2) * 72 + bk2[i]]) = pkbf(pb0[i].z, pb1[i].z);
                *reinterpret_cast<unsigned int*>(&Bs[(bp0[i] + 3) * 72 + bk2[i]]) = pkbf(pb0[i].w, pb1[i].w);
            }
            __syncthreads();
        }
    }
    // atomic accumulate G[s][b][p][m] (two kh blocks per output)
    int b = bnt;
#pragma unroll
    for (int i = 0; i < 3; ++i)
#pragma unroll
        for (int j = 0; j < 2; ++j)
#pragma unroll
            for (int r = 0; r < 4; ++r) {
                int p = ph * 48 + i * 16 + quad * 4 + r;
                int m = mh * 32 + j * 16 + col;
                atomicAdd(&G[(((size_t)s * BATCH + b) * PRED + p) * NVAR + m],
                          acc[i][j][r]);
            }
}

// ---------------- out partials (+ fused softmax + regularizer) --------------
__global__ __launch_bounds__(256) void out_partial(
    const float* __restrict__ e1, const float* __restrict__ e2,
    const float* __restrict__ G, float* __restrict__ partial,
    float* __restrict__ regacc) {
    __shared__ float adjn[2][32][65];
    __shared__ float Gs[96][65];
    __shared__ float e2s[3][64][8];
    __shared__ float e1s[3][32][8];
    __shared__ float wsum[4];
    int b = blockIdx.x, sg = blockIdx.y, nh = blockIdx.z;
    int s0 = sg * 2;
    int wv = threadIdx.x >> 6, lane = threadIdx.x & 63;

    // stage e1/e2 slices for s = s0-1, s0, s0+1 (zero-fill s<0)
    for (int idx = threadIdx.x; idx < 3 * 64 * 8; idx += 256) {
        int j = idx >> 9, m = (idx >> 3) & 63, r = idx & 7;
        int s = s0 - 1 + j;
        e2s[j][m][r] = (s >= 0)
            ? e2[(((size_t)b * SEG + s) * NVAR + m) * RNK + r] : 0.0f;
    }
    for (int idx = threadIdx.x; idx < 3 * 32 * 8; idx += 256) {
        int j = idx >> 8, nl = (idx >> 3) & 31, r = idx & 7;
        int s = s0 - 1 + j;
        e1s[j][nl][r] = (s >= 0)
            ? e1[(((size_t)b * SEG + s) * NVAR + nh * 32 + nl) * RNK + r] : 0.0f;
    }
    __syncthreads();

    // compute adj rows (lane = m); wave wv handles rows wv*8..wv*8+7
    float regsum = 0.0f;
    for (int t = 0; t < 8; ++t) {
        int nl = wv * 8 + t;
        float a[3];
#pragma unroll
        for (int j = 0; j < 3; ++j) {
            float sc = 0.0f;
#pragma unroll
            for (int r = 0; r < 8; ++r) sc += e1s[j][nl][r] * e2s[j][lane][r];
            sc *= 0.35355339059327373f;  // 1/sqrt(8)
            float mx = sc;
            for (int off = 32; off; off >>= 1)
                mx = fmaxf(mx, __shfl_xor(mx, off, 64));
            float ex = __expf(sc - mx);
            float sm = ex;
            for (int off = 32; off; off >>= 1) sm += __shfl_xor(sm, off, 64);
            a[j] = ex * __builtin_amdgcn_rcpf(sm);
        }
        if (s0 > 0) regsum += fabsf(a[1] - a[0]);  // diff at s0 (vs s0-1)
        regsum += fabsf(a[2] - a[1]);              // diff at s0+1 (vs s0)
        adjn[0][nl][lane] = a[1];
        adjn[1][nl][lane] = a[2];
    }
    __syncthreads();

    int pg = threadIdx.x >> 4;   // p = pg*6 + j
    int ng = threadIdx.x & 15;   // n = nh*32 + ng*2 + i
    float acc[6][2];
#pragma unroll
    for (int j = 0; j < 6; ++j) { acc[j][0] = 0.f; acc[j][1] = 0.f; }

#pragma unroll
    for (int ss = 0; ss < 2; ++ss) {
        int s = s0 + ss;
#pragma unroll
        for (int i = 0; i < 6; ++i) {
            int q = threadIdx.x + 256 * i;
            int row = q >> 4, mq = (q & 15) * 4;
            float4 v = *reinterpret_cast<const float4*>(
                &G[(((size_t)s * BATCH + b) * PRED + row) * NVAR + mq]);
            Gs[row][mq + 0] = v.x; Gs[row][mq + 1] = v.y;
            Gs[row][mq + 2] = v.z; Gs[row][mq + 3] = v.w;
        }
        __syncthreads();
#pragma unroll 4
        for (int m = 0; m < 64; ++m) {
            float a0 = adjn[ss][ng * 2 + 0][m];
            float a1 = adjn[ss][ng * 2 + 1][m];
#pragma unroll
            for (int j = 0; j < 6; ++j) {
                float g = Gs[pg * 6 + j][m];
                acc[j][0] += g * a0;
                acc[j][1] += g * a1;
            }
        }
        __syncthreads();
    }
#pragma unroll
    for (int j = 0; j < 6; ++j)
#pragma unroll
        for (int i = 0; i < 2; ++i) {
            int p = pg * 6 + j, n = nh * 32 + ng * 2 + i;
            partial[(((size_t)sg * BATCH + b) * PRED + p) * NVAR + n] = acc[j][i];
        }
    // block-reduce regsum -> one atomic
    for (int off = 32; off; off >>= 1) regsum += __shfl_xor(regsum, off, 64);
    if (lane == 0) wsum[wv] = regsum;
    __syncthreads();
    if (threadIdx.x == 0)
        atomicAdd(regacc, wsum[0] + wsum[1] + wsum[2] + wsum[3]);
}

// ---------------- reduce 16 partials + head_b (float4); write reg -----------
__global__ __launch_bounds__(256) void out_reduce(
    const float* __restrict__ partial, const float* __restrict__ head_b,
    const float* __restrict__ regacc, float* __restrict__ out, int out_size) {
    int i4 = blockIdx.x * 256 + threadIdx.x;  // 0..24575 float4s
    int p = (i4 >> 4) % PRED;
    float hb = head_b[p];
    float4 a = make_float4(hb, hb, hb, hb);
    const int stride4 = BATCH * PRED * NVAR / 4;
    const float4* p4 = reinterpret_cast<const float4*>(partial);
#pragma unroll
    for (int sg = 0; sg < 16; ++sg) {
        float4 v = p4[sg * stride4 + i4];
        a.x += v.x; a.y += v.y; a.z += v.z; a.w += v.w;
    }
    reinterpret_cast<float4*>(out)[i4] = a;
    if (i4 == 0) out[out_size - 1] = regacc[0] * (1.0f / 65536.0f);
}

extern "C" void kernel_launch(void* const* d_in, const int* in_sizes, int n_in,
                              void* d_out, int out_size, void* d_ws,
                              size_t ws_size, hipStream_t stream) {
    const float* x_enc  = (const float*)d_in[0];
    const float* w_emb  = (const float*)d_in[4];
    const float* b_emb  = (const float*)d_in[5];
    const float* conv_w = (const float*)d_in[6];
    const float* conv_b = (const float*)d_in[7];
    const float* gg_w1  = (const float*)d_in[8];
    const float* gg_b1  = (const float*)d_in[9];
    const float* gg_w2  = (const float*)d_in[10];
    const float* gg_b2  = (const float*)d_in[11];
    const float* head_w = (const float*)d_in[12];
    const float* head_b = (const float*)d_in[13];
    float* out = (float*)d_out;

    // workspace: 157,286,404 B total (proven). WTf in the former adj slot;
    // partial overlaps h2 (dead after g_gemm).
    char* ws = (char*)d_ws;
    ushort_t* h2   = (ushort_t*)(ws);                   // 134,217,728
    float* partial = (float*)(ws);                      //   6,291,456 (overlaps h2)
    float* G       = (float*)(ws + 134217728);          //  12,582,912
    float* e1      = (float*)(ws + 146800640);          //   1,048,576
    float* e2      = (float*)(ws + 147849216);          //   1,048,576
    ushort_t* WTf  = (ushort_t*)(ws + 148897792);       //     196,608
    float* regacc  = (float*)(ws + 157286400);          //           4

    hipMemsetAsync(G, 0, 12582912, stream);  // zero G for split-K atomics
    wt_prep<<<dim3(6, 128), 128, 0, stream>>>(conv_w, WTf, regacc);
    tcn_mfma<<<dim3(BN, SEQ / 64), 256, 0, stream>>>(
        x_enc, w_emb, b_emb, WTf, conv_b,
        gg_w1, gg_b1, gg_w2, gg_b2, h2, e1, e2);
    g_gemm<<<dim3(SEG, BATCH, 2), 256, 0, stream>>>(h2, head_w, G);
    out_partial<<<dim3(BATCH, 16, 2), 256, 0, stream>>>(
        e1, e2, G, partial, regacc);
    out_reduce<<<BATCH * PRED * NVAR / 1024, 256, 0, stream>>>(
        partial, head_b, regacc, out, out_size);
}